// Round 5
// baseline (2162.812 us; speedup 1.0000x reference)
//
#include <hip/hip_runtime.h>
#include <math.h>

#define NH 16
#define SEQ 2048
#define DIM 128
#define NMEM 4096
#define TOPK 16
#define TQ 64          // queries per workgroup -> grid 512 -> 2 blocks/CU
#define NTILE (SEQ / TQ)     // 32 tiles per head
#define KC 64          // keys per chunk
#define NCHUNK (NMEM / KC)   // 64
#define QBS 136        // bf16 Q stride (272 B rows: 16B-aligned + 4-bank row advance)
#define KBS 136        // bf16 K stride
#define SST 68         // sims stride (fp32)
#define QHS 132        // fp32 qhat stride
#define NTHR 512
#define HROWS 32       // rows per phase-b pass

typedef short bf16x8 __attribute__((ext_vector_type(8)));
typedef float f32x4  __attribute__((ext_vector_type(4)));

// pack two fp32 -> bf16x2 (round-to-nearest-even; finite inputs)
__device__ __forceinline__ unsigned f2bf2(float lo, float hi) {
    union { float f; unsigned u; } a, b;
    a.f = lo; b.f = hi;
    unsigned ra = (a.u + 0x7fffu + ((a.u >> 16) & 1u)) >> 16;
    unsigned rb = (b.u + 0x7fffu + ((b.u >> 16) & 1u)) & 0xffff0000u;
    return ra | rb;
}

__global__ __launch_bounds__(NTHR, 4)
void praxis_fused(const float* __restrict__ query,
                  const float* __restrict__ outputs,
                  const float* __restrict__ gate,
                  const float* __restrict__ kmem,
                  const float* __restrict__ vmem,
                  float* __restrict__ out)
{
    // phase a: 52224 B, phase b: 53760 B -> union 53760 B -> 2 blocks/CU.
    __shared__ union SM {
        struct { unsigned short Qb[TQ * QBS]; unsigned short Kb[KC * KBS];
                 float Sc[TQ * SST]; } a;                                   // 52224 B
        struct { float qh[HROWS * QHS]; float fs[HROWS][128]; int fi[HROWS][128];
                 float tks[HROWS][TOPK]; int tki[HROWS][TOPK]; } b;         // 53760 B
    } sm;

    const int tid = threadIdx.x;
    // XCD-aware bijective swizzle (nwg=512=8*64 exact): XCD x owns logical blocks
    // 64x..64x+63 = heads 2x,2x+1 -> per-XCD K+V gather working set ~8 MB streamed,
    // 4 MB resident per phase (fits L2).
    const int lb = ((blockIdx.x & 7) << 6) | ((int)blockIdx.x >> 3);
    const int h  = lb >> 5;                // NTILE=32 q-tiles per head
    const int q0 = (lb & 31) * TQ;

    const float* Qg = query + ((size_t)h * SEQ + q0) * DIM;
    const float* Kg = kmem + (size_t)h * NMEM * DIM;
    const float* Vg = vmem + (size_t)h * NMEM * DIM;

    // ---- build bf16 Qb from global (pool-only precision; 8 thr/row) ----
    {
        int row = tid >> 3, part = tid & 7;       // 64 rows x 8 threads, 16 dims each
        const float* qp = Qg + (size_t)row * DIM + part * 16;
        float4 v[4];
        float ss = 0.f;
#pragma unroll
        for (int j = 0; j < 4; ++j) {
            v[j] = *(const float4*)(qp + j * 4);
            ss = fmaf(v[j].x, v[j].x, ss); ss = fmaf(v[j].y, v[j].y, ss);
            ss = fmaf(v[j].z, v[j].z, ss); ss = fmaf(v[j].w, v[j].w, ss);
        }
        ss += __shfl_xor(ss, 1);
        ss += __shfl_xor(ss, 2);
        ss += __shfl_xor(ss, 4);
        float inv = 1.0f / fmaxf(sqrtf(ss), 1e-6f);
#pragma unroll
        for (int j = 0; j < 4; ++j) {
            unsigned lo = f2bf2(v[j].x * inv, v[j].y * inv);
            unsigned hi = f2bf2(v[j].z * inv, v[j].w * inv);
            *(uint2*)(&sm.a.Qb[row * QBS + part * 16 + j * 4]) = make_uint2(lo, hi);
        }
    }

    // per-thread running top-16 (SORTED ascending; ls[0] is the threshold)
    float ls[TOPK]; int li[TOPK];
#pragma unroll
    for (int t = 0; t < TOPK; ++t) { ls[t] = -1e30f; li[t] = 0; }

    // preload K chunk 0 (64 keys x 128 dims = 2048 f4 / 512 thr = 4 each)
    float4 kreg[4];
#pragma unroll
    for (int j = 0; j < 4; ++j)
        kreg[j] = *(const float4*)(Kg + (size_t)(j * NTHR + tid) * 4);

    __syncthreads();   // Qb ready

    for (int c = 0; c < NCHUNK; ++c) {
        // ---- normalize K in registers (pool-only), write bf16 Kb ----
        // kreg[j] = key row (j*16 + tid>>5), dims (tid&31)*4..+4; reduce over 32 lanes
        {
            float ssk[4];
#pragma unroll
            for (int j = 0; j < 4; ++j)
                ssk[j] = kreg[j].x*kreg[j].x + kreg[j].y*kreg[j].y +
                         kreg[j].z*kreg[j].z + kreg[j].w*kreg[j].w;
#pragma unroll
            for (int off = 1; off < 32; off <<= 1) {
#pragma unroll
                for (int j = 0; j < 4; ++j) ssk[j] += __shfl_xor(ssk[j], off);
            }
            int rrow = tid >> 5, c4 = tid & 31;
#pragma unroll
            for (int j = 0; j < 4; ++j) {
                float inv = 1.0f / fmaxf(sqrtf(ssk[j]), 1e-6f);
                unsigned lo = f2bf2(kreg[j].x * inv, kreg[j].y * inv);
                unsigned hi = f2bf2(kreg[j].z * inv, kreg[j].w * inv);
                *(uint2*)(&sm.a.Kb[(rrow + 16 * j) * KBS + c4 * 4]) = make_uint2(lo, hi);
            }
        }
        __syncthreads();  // (1) Kb ready; prior filter's Sc reads done

        // prefetch next chunk (in flight across MFMA; drains at barrier 2)
        if (c + 1 < NCHUNK) {
            const float* base = Kg + (size_t)(c + 1) * KC * DIM;
#pragma unroll
            for (int j = 0; j < 4; ++j)
                kreg[j] = *(const float4*)(base + (size_t)(j * NTHR + tid) * 4);
        }

        // ---- sims via MFMA: wave w -> q-band (w&3), key-half (w>>2) ----
        // verified pattern (m89/m92): C/D row=(lane>>4)*4+r, col=lane&15
        {
            const int w = tid >> 6, lane = tid & 63;
            const int band = w & 3, kh = w >> 2;
            const int l15 = lane & 15, lg = lane >> 4;
            const unsigned short* qb = &sm.a.Qb[(16 * band + l15) * QBS + lg * 8];
            const unsigned short* kb = &sm.a.Kb[(32 * kh + l15) * KBS + lg * 8];
            f32x4 a0 = {0.f, 0.f, 0.f, 0.f};
            f32x4 a1 = a0;
#pragma unroll
            for (int kk = 0; kk < 4; ++kk) {
                bf16x8 af = *(const bf16x8*)(qb + kk * 32);
                bf16x8 b0 = *(const bf16x8*)(kb + kk * 32);
                bf16x8 b1 = *(const bf16x8*)(kb + 16 * KBS + kk * 32);
                a0 = __builtin_amdgcn_mfma_f32_16x16x32_bf16(af, b0, a0, 0, 0, 0);
                a1 = __builtin_amdgcn_mfma_f32_16x16x32_bf16(af, b1, a1, 0, 0, 0);
            }
            const int orow = 16 * band + lg * 4;
#pragma unroll
            for (int r = 0; r < 4; ++r) {
                float* sp = &sm.a.Sc[(orow + r) * SST + 32 * kh + l15];
                sp[0]  = a0[r];
                sp[16] = a1[r];
            }
        }
        __syncthreads();  // (2) Sc ready; Kb consumed; prefetch drained

        // ---- top-k filter: 8 thr/row, 8 keys each (2 groups of 4) ----
        {
            int row = tid >> 3, part = tid & 7;
            const float* scr = &sm.a.Sc[row * SST + part * 8];
            float4 vv[2];
#pragma unroll
            for (int g = 0; g < 2; ++g)
                vv[g] = *(const float4*)(scr + g * 4);
            float mnv = ls[0];
#pragma unroll
            for (int g = 0; g < 2; ++g) {
                float4 v = vv[g];
                int b0 = c * KC + part * 8 + g * 4;
                float m01 = fmaxf(v.x, v.y); int i01 = (v.x >= v.y) ? 0 : 1;
                float m23 = fmaxf(v.z, v.w); int i23 = (v.z >= v.w) ? 2 : 3;
                float m   = fmaxf(m01, m23); int im  = (m01 >= m23) ? i01 : i23;
                while (__ballot(m > mnv)) {
                    if (m > mnv) {
                        float s = m; int id = b0 + im;
                        bool bp = true;
#pragma unroll
                        for (int t = 0; t < TOPK - 1; ++t) {
                            bool bt = s > ls[t + 1];
                            float nv = bt ? ls[t + 1] : (bp ? s : ls[t]);
                            int   ni = bt ? li[t + 1] : (bp ? id : li[t]);
                            ls[t] = nv; li[t] = ni; bp = bt;
                        }
                        ls[TOPK - 1] = bp ? s : ls[TOPK - 1];
                        li[TOPK - 1] = bp ? id : li[TOPK - 1];
                        mnv = ls[0];
                        v.x = (im == 0) ? -3e38f : v.x;
                        v.y = (im == 1) ? -3e38f : v.y;
                        v.z = (im == 2) ? -3e38f : v.z;
                        v.w = (im == 3) ? -3e38f : v.w;
                        m01 = fmaxf(v.x, v.y); i01 = (v.x >= v.y) ? 0 : 1;
                        m23 = fmaxf(v.z, v.w); i23 = (v.z >= v.w) ? 2 : 3;
                        m   = fmaxf(m01, m23); im  = (m01 >= m23) ? i01 : i23;
                    }
                }
            }
        }
        // no barrier: next iter's Kb write is after barrier (1); Sc reuse ordered by (1)
    }

    // ---- phase b: two passes of 32 rows (LDS-limited) ----
#pragma unroll 1
    for (int p = 0; p < 2; ++p) {
        __syncthreads();   // Sc reads done (p=0) / prior pass done (p=1)
        // dump pool indices for this row-half (256 threads)
        {
            int row = tid >> 3;
            if ((row >> 5) == p) {
                int lr = row & 31, part = tid & 7;
#pragma unroll
                for (int t = 0; t < TOPK; ++t)
                    sm.b.fi[lr][part * TOPK + t] = li[t];
            }
        }
        // build qh = r0-bit-exact normalized q rows (fp32) for this half (128 threads)
        if (tid < 128) {
            int lr = tid >> 2, part = tid & 3;
            const float* qp = query + ((size_t)h * SEQ + q0 + p * HROWS + lr) * DIM + part * 32;
            float4 v[8];
            float ss = 0.f;
#pragma unroll
            for (int j = 0; j < 8; ++j) {
                v[j] = *(const float4*)(qp + j * 4);
                ss = fmaf(v[j].x, v[j].x, ss); ss = fmaf(v[j].y, v[j].y, ss);
                ss = fmaf(v[j].z, v[j].z, ss); ss = fmaf(v[j].w, v[j].w, ss);
            }
            ss += __shfl_xor(ss, 1);
            ss += __shfl_xor(ss, 2);
            float inv = 1.0f / fmaxf(sqrtf(ss), 1e-6f);
#pragma unroll
            for (int j = 0; j < 8; ++j) {
                float4 s;
                s.x = v[j].x * inv; s.y = v[j].y * inv;
                s.z = v[j].z * inv; s.w = v[j].w * inv;
                *(float4*)(&sm.b.qh[lr * QHS + part * 32 + j * 4]) = s;
            }
        }
        __syncthreads();
        // ---- rescore: r0-bit-exact; 16 thr/row x 8 candidates each ----
        {
            int lr = tid >> 4;
            int s0 = (tid & 15) * 8;
            const float* qh = &sm.b.qh[lr * QHS];
#pragma unroll 2
            for (int s = 0; s < 8; ++s) {
                int slot = s0 + s;
                int idx = sm.b.fi[lr][slot];
                const float* kp = Kg + (size_t)idx * DIM;
                float sp[8];
#pragma unroll
                for (int pp = 0; pp < 8; ++pp) {
                    float sacc = 0.f;
#pragma unroll
                    for (int j = 0; j < 4; ++j) {
                        float4 kv = *(const float4*)(kp + pp * 16 + j * 4);
                        sacc = fmaf(kv.x, kv.x, sacc); sacc = fmaf(kv.y, kv.y, sacc);
                        sacc = fmaf(kv.z, kv.z, sacc); sacc = fmaf(kv.w, kv.w, sacc);
                    }
                    sp[pp] = sacc;
                }
                float kss = ((sp[0] + sp[1]) + (sp[2] + sp[3])) +
                            ((sp[4] + sp[5]) + (sp[6] + sp[7]));
                float kinv = 1.0f / fmaxf(sqrtf(kss), 1e-6f);
                float acc = 0.f;
#pragma unroll
                for (int d4 = 0; d4 < 32; ++d4) {
                    float4 qa = *(const float4*)(qh + d4 * 4);
                    float4 kv = *(const float4*)(kp + d4 * 4);
                    acc = fmaf(qa.x, kv.x * kinv, acc);
                    acc = fmaf(qa.y, kv.y * kinv, acc);
                    acc = fmaf(qa.z, kv.z * kinv, acc);
                    acc = fmaf(qa.w, kv.w * kinv, acc);
                }
                sm.b.fs[lr][slot] = acc;
            }
        }
        __syncthreads();
        // ---- selection: wave per 4 rows; 16 rounds of wave-max over 128 cands ----
        // Tie-break by SMALLEST index (matches jax.lax.top_k stability).
        {
            int wv = tid >> 6, lane = tid & 63;
#pragma unroll 1
            for (int rr = 0; rr < 4; ++rr) {
                int lr = wv * 4 + rr;
                float sA = sm.b.fs[lr][lane];      int idA = sm.b.fi[lr][lane];
                float sB = sm.b.fs[lr][lane + 64]; int idB = sm.b.fi[lr][lane + 64];
#pragma unroll 1
                for (int it = 0; it < TOPK; ++it) {
                    float m = fmaxf(sA, sB);
#pragma unroll
                    for (int off = 32; off >= 1; off >>= 1)
                        m = fmaxf(m, __shfl_xor(m, off));
                    int c0 = (sA == m) ? idA : 0x7FFFFFFF;
                    int c1 = (sB == m) ? idB : 0x7FFFFFFF;
                    int cand = min(c0, c1);
#pragma unroll
                    for (int off = 32; off >= 1; off >>= 1)
                        cand = min(cand, __shfl_xor(cand, off));
                    if (lane == 0) { sm.b.tks[lr][it] = m; sm.b.tki[lr][it] = cand; }
                    if (sA == m && idA == cand) sA = -3e38f;
                    if (sB == m && idB == cand) sB = -3e38f;
                }
            }
        }
        __syncthreads();
        // ---- epilogue: 16 thr/row x 8 dims; gather V, weighted sum, gate blend ----
        {
            int lr = tid >> 4, part = tid & 15;
            float4 acc[2];
            acc[0] = make_float4(0.f, 0.f, 0.f, 0.f);
            acc[1] = make_float4(0.f, 0.f, 0.f, 0.f);
#pragma unroll 1
            for (int t = 0; t < TOPK; ++t) {
                float s = sm.b.tks[lr][t];
                int idx = sm.b.tki[lr][t] & (NMEM - 1);
                const float* vp = Vg + (size_t)idx * DIM + part * 8;
#pragma unroll
                for (int j = 0; j < 2; ++j) {
                    float4 v = *(const float4*)(vp + j * 4);
                    acc[j].x = fmaf(s, v.x, acc[j].x);
                    acc[j].y = fmaf(s, v.y, acc[j].y);
                    acc[j].z = fmaf(s, v.z, acc[j].z);
                    acc[j].w = fmaf(s, v.w, acc[j].w);
                }
            }
            float g = 1.0f / (1.0f + expf(-gate[h]));
            float og = 1.0f - g;
            size_t ob = ((size_t)h * SEQ + q0 + p * HROWS + lr) * DIM + part * 8;
#pragma unroll
            for (int j = 0; j < 2; ++j) {
                float4 o = *(const float4*)(outputs + ob + j * 4);
                float4 r;
                r.x = g * acc[j].x + og * o.x;
                r.y = g * acc[j].y + og * o.y;
                r.z = g * acc[j].z + og * o.z;
                r.w = g * acc[j].w + og * o.w;
                *(float4*)(out + ob + j * 4) = r;
            }
        }
    }
}

extern "C" void kernel_launch(void* const* d_in, const int* in_sizes, int n_in,
                              void* d_out, int out_size, void* d_ws, size_t ws_size,
                              hipStream_t stream) {
    (void)in_sizes; (void)n_in; (void)out_size; (void)d_ws; (void)ws_size;
    const float* query   = (const float*)d_in[1];
    const float* outputs = (const float*)d_in[4];
    const float* gate    = (const float*)d_in[5];
    const float* kmem    = (const float*)d_in[6];
    const float* vmem    = (const float*)d_in[7];
    float* out = (float*)d_out;
    dim3 grid(NH * NTILE);  // 512 workgroups -> 2 per CU
    praxis_fused<<<grid, NTHR, 0, stream>>>(query, outputs, gate, kmem, vmem, out);
}

// Round 6
// 1610.979 us; speedup vs baseline: 1.3425x; 1.3425x over previous
//
#include <hip/hip_runtime.h>
#include <math.h>

#define NH 16
#define SEQ 2048
#define DIM 128
#define NMEM 4096
#define TOPK 16
#define TQ 64          // queries per workgroup -> grid 512 -> 2 blocks/CU
#define NTILE (SEQ / TQ)     // 32 tiles per head
#define KC 64          // keys per chunk
#define NCHUNK (NMEM / KC)   // 64
#define QBS 136        // bf16 Q stride (272 B rows: 16B-aligned + 4-bank row advance)
#define KBS 136        // bf16 K stride
#define SST 68         // sims stride (fp32)
#define QHS 132        // fp32 qhat stride
#define NTHR 512
#define HROWS 32       // rows per phase-b pass

typedef short bf16x8 __attribute__((ext_vector_type(8)));
typedef float f32x4  __attribute__((ext_vector_type(4)));

// pack two fp32 -> bf16x2 (round-to-nearest-even; finite inputs)
__device__ __forceinline__ unsigned f2bf2(float lo, float hi) {
    union { float f; unsigned u; } a, b;
    a.f = lo; b.f = hi;
    unsigned ra = (a.u + 0x7fffu + ((a.u >> 16) & 1u)) >> 16;
    unsigned rb = (b.u + 0x7fffu + ((b.u >> 16) & 1u)) & 0xffff0000u;
    return ra | rb;
}

// launch_bounds 2nd arg is min BLOCKS/CU on this hipcc (measured: (512,2)->cap 128 VGPR,
// (512,4)->cap 64 VGPR + catastrophic spill). 2 blocks/CU => 128-VGPR cap, fits spill-free.
__global__ __launch_bounds__(NTHR, 2)
void praxis_fused(const float* __restrict__ query,
                  const float* __restrict__ outputs,
                  const float* __restrict__ gate,
                  const float* __restrict__ kmem,
                  const float* __restrict__ vmem,
                  float* __restrict__ out)
{
    // phase a: 52224 B, phase b: 53760 B -> union 53760 B -> 2 blocks/CU by LDS.
    __shared__ union SM {
        struct { unsigned short Qb[TQ * QBS]; unsigned short Kb[KC * KBS];
                 float Sc[TQ * SST]; } a;                                   // 52224 B
        struct { float qh[HROWS * QHS]; float fs[HROWS][128]; int fi[HROWS][128];
                 float tks[HROWS][TOPK]; int tki[HROWS][TOPK]; } b;         // 53760 B
    } sm;

    const int tid = threadIdx.x;
    // XCD-aware bijective swizzle (nwg=512=8*64 exact): XCD x owns logical blocks
    // 64x..64x+63 = heads 2x,2x+1 -> per-XCD gather working set fits L2.
    const int lb = ((blockIdx.x & 7) << 6) | ((int)blockIdx.x >> 3);
    const int h  = lb >> 5;                // NTILE=32 q-tiles per head
    const int q0 = (lb & 31) * TQ;

    const float* Qg = query + ((size_t)h * SEQ + q0) * DIM;
    const float* Kg = kmem + (size_t)h * NMEM * DIM;
    const float* Vg = vmem + (size_t)h * NMEM * DIM;

    // ---- build bf16 Qb from global (pool-only precision; 8 thr/row) ----
    {
        int row = tid >> 3, part = tid & 7;       // 64 rows x 8 threads, 16 dims each
        const float* qp = Qg + (size_t)row * DIM + part * 16;
        float4 v[4];
        float ss = 0.f;
#pragma unroll
        for (int j = 0; j < 4; ++j) {
            v[j] = *(const float4*)(qp + j * 4);
            ss = fmaf(v[j].x, v[j].x, ss); ss = fmaf(v[j].y, v[j].y, ss);
            ss = fmaf(v[j].z, v[j].z, ss); ss = fmaf(v[j].w, v[j].w, ss);
        }
        ss += __shfl_xor(ss, 1);
        ss += __shfl_xor(ss, 2);
        ss += __shfl_xor(ss, 4);
        float inv = 1.0f / fmaxf(sqrtf(ss), 1e-6f);
#pragma unroll
        for (int j = 0; j < 4; ++j) {
            unsigned lo = f2bf2(v[j].x * inv, v[j].y * inv);
            unsigned hi = f2bf2(v[j].z * inv, v[j].w * inv);
            *(uint2*)(&sm.a.Qb[row * QBS + part * 16 + j * 4]) = make_uint2(lo, hi);
        }
    }

    // per-thread running top-16 (SORTED ascending; ls[0] is the threshold)
    float ls[TOPK]; int li[TOPK];
#pragma unroll
    for (int t = 0; t < TOPK; ++t) { ls[t] = -1e30f; li[t] = 0; }

    // preload K chunk 0 (64 keys x 128 dims = 2048 f4 / 512 thr = 4 each)
    float4 kreg[4];
#pragma unroll
    for (int j = 0; j < 4; ++j)
        kreg[j] = *(const float4*)(Kg + (size_t)(j * NTHR + tid) * 4);

    __syncthreads();   // Qb ready

    for (int c = 0; c < NCHUNK; ++c) {
        // ---- normalize K in registers (pool-only), write bf16 Kb ----
        // kreg[j] = key row (j*16 + tid>>5), dims (tid&31)*4..+4; reduce over 32 lanes
        {
            float ssk[4];
#pragma unroll
            for (int j = 0; j < 4; ++j)
                ssk[j] = kreg[j].x*kreg[j].x + kreg[j].y*kreg[j].y +
                         kreg[j].z*kreg[j].z + kreg[j].w*kreg[j].w;
#pragma unroll
            for (int off = 1; off < 32; off <<= 1) {
#pragma unroll
                for (int j = 0; j < 4; ++j) ssk[j] += __shfl_xor(ssk[j], off);
            }
            int rrow = tid >> 5, c4 = tid & 31;
#pragma unroll
            for (int j = 0; j < 4; ++j) {
                float inv = 1.0f / fmaxf(sqrtf(ssk[j]), 1e-6f);
                unsigned lo = f2bf2(kreg[j].x * inv, kreg[j].y * inv);
                unsigned hi = f2bf2(kreg[j].z * inv, kreg[j].w * inv);
                *(uint2*)(&sm.a.Kb[(rrow + 16 * j) * KBS + c4 * 4]) = make_uint2(lo, hi);
            }
        }
        __syncthreads();  // (1) Kb ready; prior filter's Sc reads done

        // prefetch next chunk (in flight across MFMA; drains at barrier 2)
        if (c + 1 < NCHUNK) {
            const float* base = Kg + (size_t)(c + 1) * KC * DIM;
#pragma unroll
            for (int j = 0; j < 4; ++j)
                kreg[j] = *(const float4*)(base + (size_t)(j * NTHR + tid) * 4);
        }

        // ---- sims via MFMA: wave w -> q-band (w&3), key-half (w>>2) ----
        // verified pattern (m89/m92): C/D row=(lane>>4)*4+r, col=lane&15
        {
            const int w = tid >> 6, lane = tid & 63;
            const int band = w & 3, kh = w >> 2;
            const int l15 = lane & 15, lg = lane >> 4;
            const unsigned short* qb = &sm.a.Qb[(16 * band + l15) * QBS + lg * 8];
            const unsigned short* kb = &sm.a.Kb[(32 * kh + l15) * KBS + lg * 8];
            f32x4 a0 = {0.f, 0.f, 0.f, 0.f};
            f32x4 a1 = a0;
#pragma unroll
            for (int kk = 0; kk < 4; ++kk) {
                bf16x8 af = *(const bf16x8*)(qb + kk * 32);
                bf16x8 b0 = *(const bf16x8*)(kb + kk * 32);
                bf16x8 b1 = *(const bf16x8*)(kb + 16 * KBS + kk * 32);
                a0 = __builtin_amdgcn_mfma_f32_16x16x32_bf16(af, b0, a0, 0, 0, 0);
                a1 = __builtin_amdgcn_mfma_f32_16x16x32_bf16(af, b1, a1, 0, 0, 0);
            }
            const int orow = 16 * band + lg * 4;
#pragma unroll
            for (int r = 0; r < 4; ++r) {
                float* sp = &sm.a.Sc[(orow + r) * SST + 32 * kh + l15];
                sp[0]  = a0[r];
                sp[16] = a1[r];
            }
        }
        __syncthreads();  // (2) Sc ready; Kb consumed; prefetch drained

        // ---- top-k filter: 8 thr/row, 8 keys each (2 groups of 4) ----
        {
            int row = tid >> 3, part = tid & 7;
            const float* scr = &sm.a.Sc[row * SST + part * 8];
            float4 vv[2];
#pragma unroll
            for (int g = 0; g < 2; ++g)
                vv[g] = *(const float4*)(scr + g * 4);
            float mnv = ls[0];
#pragma unroll
            for (int g = 0; g < 2; ++g) {
                float4 v = vv[g];
                int b0 = c * KC + part * 8 + g * 4;
                float m01 = fmaxf(v.x, v.y); int i01 = (v.x >= v.y) ? 0 : 1;
                float m23 = fmaxf(v.z, v.w); int i23 = (v.z >= v.w) ? 2 : 3;
                float m   = fmaxf(m01, m23); int im  = (m01 >= m23) ? i01 : i23;
                while (__ballot(m > mnv)) {
                    if (m > mnv) {
                        float s = m; int id = b0 + im;
                        bool bp = true;
#pragma unroll
                        for (int t = 0; t < TOPK - 1; ++t) {
                            bool bt = s > ls[t + 1];
                            float nv = bt ? ls[t + 1] : (bp ? s : ls[t]);
                            int   ni = bt ? li[t + 1] : (bp ? id : li[t]);
                            ls[t] = nv; li[t] = ni; bp = bt;
                        }
                        ls[TOPK - 1] = bp ? s : ls[TOPK - 1];
                        li[TOPK - 1] = bp ? id : li[TOPK - 1];
                        mnv = ls[0];
                        v.x = (im == 0) ? -3e38f : v.x;
                        v.y = (im == 1) ? -3e38f : v.y;
                        v.z = (im == 2) ? -3e38f : v.z;
                        v.w = (im == 3) ? -3e38f : v.w;
                        m01 = fmaxf(v.x, v.y); i01 = (v.x >= v.y) ? 0 : 1;
                        m23 = fmaxf(v.z, v.w); i23 = (v.z >= v.w) ? 2 : 3;
                        m   = fmaxf(m01, m23); im  = (m01 >= m23) ? i01 : i23;
                    }
                }
            }
        }
        // no barrier: next iter's Kb write is after barrier (1); Sc reuse ordered by (1)
    }

    // ---- phase b: two passes of 32 rows (LDS-limited) ----
#pragma unroll 1
    for (int p = 0; p < 2; ++p) {
        __syncthreads();   // Sc reads done (p=0) / prior pass done (p=1)
        // dump pool indices for this row-half (256 threads)
        {
            int row = tid >> 3;
            if ((row >> 5) == p) {
                int lr = row & 31, part = tid & 7;
#pragma unroll
                for (int t = 0; t < TOPK; ++t)
                    sm.b.fi[lr][part * TOPK + t] = li[t];
            }
        }
        // build qh = r0-bit-exact normalized q rows (fp32) for this half (128 threads)
        if (tid < 128) {
            int lr = tid >> 2, part = tid & 3;
            const float* qp = query + ((size_t)h * SEQ + q0 + p * HROWS + lr) * DIM + part * 32;
            float4 v[8];
            float ss = 0.f;
#pragma unroll
            for (int j = 0; j < 8; ++j) {
                v[j] = *(const float4*)(qp + j * 4);
                ss = fmaf(v[j].x, v[j].x, ss); ss = fmaf(v[j].y, v[j].y, ss);
                ss = fmaf(v[j].z, v[j].z, ss); ss = fmaf(v[j].w, v[j].w, ss);
            }
            ss += __shfl_xor(ss, 1);
            ss += __shfl_xor(ss, 2);
            float inv = 1.0f / fmaxf(sqrtf(ss), 1e-6f);
#pragma unroll
            for (int j = 0; j < 8; ++j) {
                float4 s;
                s.x = v[j].x * inv; s.y = v[j].y * inv;
                s.z = v[j].z * inv; s.w = v[j].w * inv;
                *(float4*)(&sm.b.qh[lr * QHS + part * 32 + j * 4]) = s;
            }
        }
        __syncthreads();
        // ---- rescore: r0-bit-exact; 16 thr/row x 8 candidates each ----
        {
            int lr = tid >> 4;
            int s0 = (tid & 15) * 8;
            const float* qh = &sm.b.qh[lr * QHS];
#pragma unroll 2
            for (int s = 0; s < 8; ++s) {
                int slot = s0 + s;
                int idx = sm.b.fi[lr][slot];
                const float* kp = Kg + (size_t)idx * DIM;
                float sp[8];
#pragma unroll
                for (int pp = 0; pp < 8; ++pp) {
                    float sacc = 0.f;
#pragma unroll
                    for (int j = 0; j < 4; ++j) {
                        float4 kv = *(const float4*)(kp + pp * 16 + j * 4);
                        sacc = fmaf(kv.x, kv.x, sacc); sacc = fmaf(kv.y, kv.y, sacc);
                        sacc = fmaf(kv.z, kv.z, sacc); sacc = fmaf(kv.w, kv.w, sacc);
                    }
                    sp[pp] = sacc;
                }
                float kss = ((sp[0] + sp[1]) + (sp[2] + sp[3])) +
                            ((sp[4] + sp[5]) + (sp[6] + sp[7]));
                float kinv = 1.0f / fmaxf(sqrtf(kss), 1e-6f);
                float acc = 0.f;
#pragma unroll
                for (int d4 = 0; d4 < 32; ++d4) {
                    float4 qa = *(const float4*)(qh + d4 * 4);
                    float4 kv = *(const float4*)(kp + d4 * 4);
                    acc = fmaf(qa.x, kv.x * kinv, acc);
                    acc = fmaf(qa.y, kv.y * kinv, acc);
                    acc = fmaf(qa.z, kv.z * kinv, acc);
                    acc = fmaf(qa.w, kv.w * kinv, acc);
                }
                sm.b.fs[lr][slot] = acc;
            }
        }
        __syncthreads();
        // ---- selection: wave per 4 rows; 16 rounds of wave-max over 128 cands ----
        // Tie-break by SMALLEST index (matches jax.lax.top_k stability).
        {
            int wv = tid >> 6, lane = tid & 63;
#pragma unroll 1
            for (int rr = 0; rr < 4; ++rr) {
                int lr = wv * 4 + rr;
                float sA = sm.b.fs[lr][lane];      int idA = sm.b.fi[lr][lane];
                float sB = sm.b.fs[lr][lane + 64]; int idB = sm.b.fi[lr][lane + 64];
#pragma unroll 1
                for (int it = 0; it < TOPK; ++it) {
                    float m = fmaxf(sA, sB);
#pragma unroll
                    for (int off = 32; off >= 1; off >>= 1)
                        m = fmaxf(m, __shfl_xor(m, off));
                    int c0 = (sA == m) ? idA : 0x7FFFFFFF;
                    int c1 = (sB == m) ? idB : 0x7FFFFFFF;
                    int cand = min(c0, c1);
#pragma unroll
                    for (int off = 32; off >= 1; off >>= 1)
                        cand = min(cand, __shfl_xor(cand, off));
                    if (lane == 0) { sm.b.tks[lr][it] = m; sm.b.tki[lr][it] = cand; }
                    if (sA == m && idA == cand) sA = -3e38f;
                    if (sB == m && idB == cand) sB = -3e38f;
                }
            }
        }
        __syncthreads();
        // ---- epilogue: 16 thr/row x 8 dims; gather V, weighted sum, gate blend ----
        {
            int lr = tid >> 4, part = tid & 15;
            float4 acc[2];
            acc[0] = make_float4(0.f, 0.f, 0.f, 0.f);
            acc[1] = make_float4(0.f, 0.f, 0.f, 0.f);
#pragma unroll 1
            for (int t = 0; t < TOPK; ++t) {
                float s = sm.b.tks[lr][t];
                int idx = sm.b.tki[lr][t] & (NMEM - 1);
                const float* vp = Vg + (size_t)idx * DIM + part * 8;
#pragma unroll
                for (int j = 0; j < 2; ++j) {
                    float4 v = *(const float4*)(vp + j * 4);
                    acc[j].x = fmaf(s, v.x, acc[j].x);
                    acc[j].y = fmaf(s, v.y, acc[j].y);
                    acc[j].z = fmaf(s, v.z, acc[j].z);
                    acc[j].w = fmaf(s, v.w, acc[j].w);
                }
            }
            float g = 1.0f / (1.0f + expf(-gate[h]));
            float og = 1.0f - g;
            size_t ob = ((size_t)h * SEQ + q0 + p * HROWS + lr) * DIM + part * 8;
#pragma unroll
            for (int j = 0; j < 2; ++j) {
                float4 o = *(const float4*)(outputs + ob + j * 4);
                float4 r;
                r.x = g * acc[j].x + og * o.x;
                r.y = g * acc[j].y + og * o.y;
                r.z = g * acc[j].z + og * o.z;
                r.w = g * acc[j].w + og * o.w;
                *(float4*)(out + ob + j * 4) = r;
            }
        }
    }
}

extern "C" void kernel_launch(void* const* d_in, const int* in_sizes, int n_in,
                              void* d_out, int out_size, void* d_ws, size_t ws_size,
                              hipStream_t stream) {
    (void)in_sizes; (void)n_in; (void)out_size; (void)d_ws; (void)ws_size;
    const float* query   = (const float*)d_in[1];
    const float* outputs = (const float*)d_in[4];
    const float* gate    = (const float*)d_in[5];
    const float* kmem    = (const float*)d_in[6];
    const float* vmem    = (const float*)d_in[7];
    float* out = (float*)d_out;
    dim3 grid(NH * NTILE);  // 512 workgroups -> 2 per CU
    praxis_fused<<<grid, NTHR, 0, stream>>>(query, outputs, gate, kmem, vmem, out);
}